// Round 7
// baseline (250.219 us; speedup 1.0000x reference)
//
#include <hip/hip_runtime.h>
#include <cstdint>
#include <cstddef>

typedef __attribute__((ext_vector_type(8))) short short8;
typedef __attribute__((ext_vector_type(4))) float f32x4;
typedef unsigned int u32;

#define MFMA_BF16(a, b, c) __builtin_amdgcn_mfma_f32_16x16x32_bf16((a), (b), (c), 0, 0, 0)

// ---------------------------------------------------------------------------
// helpers
// ---------------------------------------------------------------------------
__device__ __forceinline__ void async16(const void* g, void* l) {
  __builtin_amdgcn_global_load_lds(
      (const __attribute__((address_space(1))) u32*)g,
      (__attribute__((address_space(3))) u32*)l, 16, 0, 0);
}

__device__ __forceinline__ short f2bf(float f) {
  u32 u = __builtin_bit_cast(u32, f);
  u += 0x7fffu + ((u >> 16) & 1u);  // round-to-nearest-even
  return (short)(u >> 16);
}

// truncating pack: [bf16(lo) | bf16(hi)<<16] in ONE v_perm_b32
__device__ __forceinline__ u32 pack_bf16_trunc(float lo, float hi) {
  return __builtin_amdgcn_perm(__builtin_bit_cast(u32, hi),
                               __builtin_bit_cast(u32, lo), 0x07060302u);
}

// ---------------------------------------------------------------------------
// fused cast fp32 -> bf16 for x, w_attn (q-rows pre-scaled), w_proj
// region sizes (float4 units): x 2097152, wa 786432 (first 262144 scaled), wp 262144
// ---------------------------------------------------------------------------
__global__ __launch_bounds__(256) void cast_all_kernel(
    const float* __restrict__ x, const float* __restrict__ wa,
    const float* __restrict__ wp, short* __restrict__ xb,
    short* __restrict__ wab, short* __restrict__ wpb) {
  const int i = blockIdx.x * blockDim.x + threadIdx.x;
  const float4* src;
  short4* dst;
  float sc = 1.0f;
  if (i < 2097152) {
    src = (const float4*)x + i;
    dst = (short4*)xb + i;
  } else if (i < 2883584) {
    const int j = i - 2097152;
    if (j < 262144) sc = 0.18033688011112042f;  // 1/sqrt(64)*log2(e)
    src = (const float4*)wa + j;
    dst = (short4*)wab + j;
  } else {
    const int j = i - 2883584;
    src = (const float4*)wp + j;
    dst = (short4*)wpb + j;
  }
  float4 v = *src;
  short4 r;
  r.x = f2bf(v.x * sc); r.y = f2bf(v.y * sc);
  r.z = f2bf(v.z * sc); r.w = f2bf(v.w * sc);
  *dst = r;
}

// ---------------------------------------------------------------------------
// r14: GEMM1 restructure — 256x256 tile, counted-vmcnt pipeline.
// Rationale: attn inner-loop micro-theories are exhausted (7 nulls, 65-70us
// plateau — structural). GEMM1 (M=8192 N=3072 K=1024, ~51.5 GF) is the
// largest non-attn kernel at the m97-style 2-barrier 128² structure
// (~850 TF ≈ 60us). Proven levers applied (m218/m230/m248 family):
//  - 256² tile, 8 waves (2M x 4N), 512 threads, per-wave 128x64 output,
//    64 MFMAs per barrier region (2x the 128² version).
//  - K dbuf: stage tile kt+1 AFTER barrier#1 (buffer freed), then
//    s_waitcnt vmcnt(8) — retires tile kt's 8 DMAs, keeps kt+1's 8 in
//    flight. NEVER vmcnt(0) mid-loop. barrier#2 publishes LDS to all waves.
//  - chunk-XOR LDS placement (proven in this harness): slot s holds
//    row=s>>3, chunk=(s&7)^(row&7); frag read chunk (kk*4+quad)^(l15&7).
//  - T5 setprio around the 32-MFMA runs (role-split now exists).
//  - bijective XCD swizzle for 384 blocks (384 = 8*48).
// LDS = 2 x 32KB x 2 = 128 KiB -> 1 block/CU, 2 waves/SIMD. 384 blocks on
// 256 CUs = 75% block-parallel efficiency (known tax, net still positive).
// ---------------------------------------------------------------------------
__global__ __launch_bounds__(512, 2) void gemm256_kernel(
    const short* __restrict__ A, const short* __restrict__ Bt,
    short* __restrict__ C) {  // M=8192, N=3072, K=1024, bf16 out
  __shared__ __align__(16) short As[2][16384];  // 256 rows x 64 k
  __shared__ __align__(16) short Bs[2][16384];

  const int tid  = threadIdx.x;
  const int lane = tid & 63;
  const int wave = tid >> 6;          // 0..7
  const int quad = lane >> 4;
  const int l15  = lane & 15;

  // bijective XCD swizzle: nwg = 384 = 8 * 48
  const int id = blockIdx.y * gridDim.x + blockIdx.x;
  const int sw = (id & 7) * 48 + (id >> 3);
  const int by = sw / 12;             // 0..31  (m-tile)
  const int bx = sw % 12;             // 0..11  (n-tile)
  const int bm = by * 256;
  const int bn = bx * 256;
  const int wm = (wave >> 2) * 128;   // 2 m-waves
  const int wn = (wave & 3) * 64;     // 4 n-waves

  f32x4 acc[8][4];
#pragma unroll
  for (int mt = 0; mt < 8; ++mt)
#pragma unroll
    for (int nt = 0; nt < 4; ++nt) acc[mt][nt] = (f32x4){0.f, 0.f, 0.f, 0.f};

  // staging: 256 rows x 8 chunks = 2048 slots per operand, 4 per thread.
  const short* abase[4];
  const short* bbase[4];
  int sdst[4];
#pragma unroll
  for (int it = 0; it < 4; ++it) {
    const int s = tid + it * 512;
    const int row = s >> 3;
    const int chunk = (s & 7) ^ (row & 7);
    abase[it] = A  + (size_t)(bm + row) * 1024 + chunk * 8;
    bbase[it] = Bt + (size_t)(bn + row) * 1024 + chunk * 8;
    sdst[it] = s * 8;
  }
  const int xk = l15 & 7;  // frag-read chunk XOR

  // prologue: stage K-tile 0 into buffer 0 (8 DMAs/thread)
#pragma unroll
  for (int it = 0; it < 4; ++it) {
    async16(abase[it], &As[0][sdst[it]]);
    async16(bbase[it], &Bs[0][sdst[it]]);
  }

  for (int kt = 0; kt < 16; ++kt) {
    // barrier#1: all waves done reading buf[(kt+1)&1] (tile kt-1's compute)
    __builtin_amdgcn_s_barrier();

    if (kt < 15) {
      const int ko = (kt + 1) * 64;
      const int nb = (kt + 1) & 1;
#pragma unroll
      for (int it = 0; it < 4; ++it) {
        async16(abase[it] + ko, &As[nb][sdst[it]]);
        async16(bbase[it] + ko, &Bs[nb][sdst[it]]);
      }
      // outstanding: tile kt's 8 + tile kt+1's 8 -> retire kt's, keep kt+1's
      asm volatile("s_waitcnt vmcnt(8)" ::: "memory");
    } else {
      asm volatile("s_waitcnt vmcnt(0)" ::: "memory");
    }
    __builtin_amdgcn_sched_barrier(0);
    __builtin_amdgcn_s_barrier();  // barrier#2: tile kt LDS-visible to all

    const short* Ab = &As[kt & 1][0];
    const short* Bb = &Bs[kt & 1][0];
#pragma unroll
    for (int kk = 0; kk < 2; ++kk) {
      short8 af[8], bf[4];
#pragma unroll
      for (int mt = 0; mt < 8; ++mt)
        af[mt] = *(const short8*)&Ab[(wm + mt * 16 + l15) * 64 +
                                     ((kk * 4 + quad) ^ xk) * 8];
#pragma unroll
      for (int nt = 0; nt < 4; ++nt)
        bf[nt] = *(const short8*)&Bb[(wn + nt * 16 + l15) * 64 +
                                     ((kk * 4 + quad) ^ xk) * 8];
      __builtin_amdgcn_s_setprio(1);
#pragma unroll
      for (int mt = 0; mt < 8; ++mt)
#pragma unroll
        for (int nt = 0; nt < 4; ++nt)
          acc[mt][nt] = MFMA_BF16(af[mt], bf[nt], acc[mt][nt]);
      __builtin_amdgcn_s_setprio(0);
    }
  }

  // epilogue: C/D layout col = lane&15, row = quad*4 + reg; bf16 out
#pragma unroll
  for (int mt = 0; mt < 8; ++mt) {
    const int r0e = bm + wm + mt * 16 + quad * 4;
#pragma unroll
    for (int nt = 0; nt < 4; ++nt) {
      const int c = bn + wn + nt * 16 + l15;
#pragma unroll
      for (int reg = 0; reg < 4; ++reg)
        C[(size_t)(r0e + reg) * 3072 + c] = f2bf(acc[mt][nt][reg]);
    }
  }
}

// ---------------------------------------------------------------------------
// C[M][N] = A[M][K] * Bt[N][K]^T   (bf16-as-short in, fp32 accumulate)
// 128x128 tile, BK=64 — unchanged known-good; used for GEMM2.
// XCD swizzle requires gridDim.y==64.
// ---------------------------------------------------------------------------
template <bool OUT_BF16>
__global__ __launch_bounds__(256) void gemm_bt_kernel(
    const short* __restrict__ A, const short* __restrict__ Bt,
    void* __restrict__ Cv, int M, int N, int K) {
  __shared__ __align__(16) short As[128 * 64];
  __shared__ __align__(16) short Bs[128 * 64];

  const int tid  = threadIdx.x;
  const int lane = tid & 63;
  const int wave = tid >> 6;
  const int quad = lane >> 4;
  const int l15  = lane & 15;

  const int id  = blockIdx.y * gridDim.x + blockIdx.x;
  const int xcd = id & 7;
  const int j   = id >> 3;
  const int by  = xcd * 8 + (j & 7);
  const int bx  = j >> 3;
  const int bm  = by * 128;
  const int bn  = bx * 128;

  const int wm = (wave >> 1) * 64;
  const int wn = (wave & 1) * 64;

  f32x4 acc[4][4];
#pragma unroll
  for (int i = 0; i < 4; ++i)
#pragma unroll
    for (int jj = 0; jj < 4; ++jj) acc[i][jj] = (f32x4){0.f, 0.f, 0.f, 0.f};

  int srow[4], scol[4];
#pragma unroll
  for (int it = 0; it < 4; ++it) {
    const int s = tid + it * 256;
    srow[it] = s >> 3;
    scol[it] = ((s & 7) ^ (srow[it] & 7)) * 8;
  }
  const int xk = l15 & 7;

  for (int k0 = 0; k0 < K; k0 += 64) {
    __syncthreads();
#pragma unroll
    for (int it = 0; it < 4; ++it) {
      const int s = tid + it * 256;
      async16(A  + (size_t)(bm + srow[it]) * K + k0 + scol[it], &As[s * 8]);
      async16(Bt + (size_t)(bn + srow[it]) * K + k0 + scol[it], &Bs[s * 8]);
    }
    __syncthreads();

    short8 af[4][2], bf[4][2];
#pragma unroll
    for (int mt = 0; mt < 4; ++mt) {
      const int ra = (wm + mt * 16 + l15) * 64;
      af[mt][0] = *(const short8*)&As[ra + ((quad) ^ xk) * 8];
      af[mt][1] = *(const short8*)&As[ra + ((4 + quad) ^ xk) * 8];
    }
#pragma unroll
    for (int nt = 0; nt < 4; ++nt) {
      const int rb = (wn + nt * 16 + l15) * 64;
      bf[nt][0] = *(const short8*)&Bs[rb + ((quad) ^ xk) * 8];
      bf[nt][1] = *(const short8*)&Bs[rb + ((4 + quad) ^ xk) * 8];
    }
#pragma unroll
    for (int kk = 0; kk < 2; ++kk)
#pragma unroll
      for (int mt = 0; mt < 4; ++mt)
#pragma unroll
        for (int nt = 0; nt < 4; ++nt)
          acc[mt][nt] = MFMA_BF16(af[mt][kk], bf[nt][kk], acc[mt][nt]);
  }

#pragma unroll
  for (int mt = 0; mt < 4; ++mt) {
    const int r0e = bm + wm + mt * 16 + quad * 4;
#pragma unroll
    for (int nt = 0; nt < 4; ++nt) {
      const int c = bn + wn + nt * 16 + l15;
#pragma unroll
      for (int reg = 0; reg < 4; ++reg) {
        float v = acc[mt][nt][reg];
        if (OUT_BF16)
          ((short*)Cv)[(size_t)(r0e + reg) * N + c] = f2bf(v);
        else
          ((float*)Cv)[(size_t)(r0e + reg) * N + c] = v;
      }
    }
  }
}

// ---------------------------------------------------------------------------
// V transpose+repack: qkv v-part [B*T][h*64+d] -> fragment-major vt2:
//   vt2[((bh*32 + kt)*8 + dt*2 + kk)*512 + (quad*16 + l15)*8 + j]
//     = V^T[d = dt*16+l15][t = kt*64 + (kk*4+quad)*8 + j]
// so an attn V-fragment load is ONE fully-coalesced 1KB global_load_dwordx4.
// ---------------------------------------------------------------------------
__global__ __launch_bounds__(256) void vtrans_kernel(
    const short* __restrict__ qkv, short* __restrict__ vt2) {
  __shared__ __align__(16) short Ts[64 * 80];
  const int kt = blockIdx.x;        // kv-tile (64 rows of t)
  const int t0 = kt * 64;
  const int bh = blockIdx.y;
  const int b = bh >> 4, h = bh & 15;
  const int tid = threadIdx.x;
#pragma unroll
  for (int it = 0; it < 2; ++it) {
    const int ci = tid + it * 256;
    const int t = ci >> 3, cw = ci & 7;
    short8 v = *(const short8*)(qkv + (size_t)(b * 2048 + t0 + t) * 3072 +
                                2048 + h * 64 + cw * 8);
    *(short8*)&Ts[t * 80 + cw * 8] = v;
  }
  __syncthreads();
#pragma unroll
  for (int it = 0; it < 2; ++it) {
    const int ci = tid + it * 256;
    const int d = ci >> 3, c2 = ci & 7;   // d = head dim, c2 = t-chunk
    short tmp[8];
#pragma unroll
    for (int j = 0; j < 8; ++j) tmp[j] = Ts[(c2 * 8 + j) * 80 + d];
    short* dst = vt2 +
        (size_t)((bh * 32 + kt) * 8 + (d >> 4) * 2 + (c2 >> 2)) * 512 +
        ((c2 & 3) * 16 + (d & 15)) * 8;
    *(short8*)dst = *(short8*)tmp;
  }
}

// ---------------------------------------------------------------------------
// Causal flash attention — EXACT r10 revert (best measured: 67.1 us).
// r11-r13 experiments (KVBLK=128, counted-vmcnt K-pipe, asm V loads) were
// regressions/nulls; plateau is structural to this 16x16 P-through-LDS
// design. Keep the best-known version untouched.
// ---------------------------------------------------------------------------
__global__ __launch_bounds__(256, 4) void attn_kernel(
    const short* __restrict__ qkv, const short* __restrict__ vt2,
    short* __restrict__ y) {
  __shared__ __align__(16) short Ks[2][4096];  // [buf][row t][64 d]
  __shared__ __align__(16) short Ps[4][1024];  // per-wave P / epilogue

  const int bh    = blockIdx.x;     // 0..63  (XCD = bh % 8 for all pairi)
  const int pairi = blockIdx.y;     // 0..15
  const int b = bh >> 4, h = bh & 15;
  const int tid  = threadIdx.x;
  const int lane = tid & 63;
  const int wave = tid >> 6;
  const int quad = lane >> 4, l15 = lane & 15;
  const int base_row = b * 2048;
  short* Pw = &Ps[wave][0];

  // K staging: slot s -> row=s>>3, chunk=(s&7)^(row&7); dst shorts s*8
  const int s0 = tid, s1 = tid + 256;
  const int r0s = s0 >> 3, c0s = (s0 & 7) ^ (r0s & 7);
  const int r1s = s1 >> 3, c1s = (s1 & 7) ^ (r1s & 7);
  const short* kbase0 = qkv + (size_t)(base_row + r0s) * 3072 + 1024 + h * 64 + c0s * 8;
  const short* kbase1 = qkv + (size_t)(base_row + r1s) * 3072 + 1024 + h * 64 + c1s * 8;

  // V fragment base: per (bh, kt) an 8KB fragment-major block; this lane's
  // slice starts at lane*8 shorts within each 1KB sub-block.
  const short* v2base = vt2 + (size_t)bh * 32 * 4096 + (size_t)lane * 8;

  const int xk = l15 & 7;  // frag-read chunk XOR

  for (int half = 0; half < 2; ++half) {
    const int qi  = half ? (31 - pairi) : pairi;  // 64-row q-tile index
    const int nkt = qi + 1;                       // kv tiles 0..qi
    const int qg0 = qi * 64 + wave * 16;          // this wave's q-group base

    // Q fragments (B-operand): lane holds Q[q=l15][d=quad*8..+7] per half
    short8 qf[2];
    {
      const short* qp = qkv +
          (size_t)(base_row + qg0 + l15) * 3072 + h * 64 + quad * 8;
      qf[0] = *(const short8*)qp;
      qf[1] = *(const short8*)(qp + 32);
    }
    float l_r = 0.f;
    f32x4 o[4];
#pragma unroll
    for (int dt = 0; dt < 4; ++dt) o[dt] = (f32x4){0.f, 0.f, 0.f, 0.f};

    // prologue: stage K-tile 0 into buffer 0
    async16(kbase0, &Ks[0][s0 * 8]);
    async16(kbase1, &Ks[0][s1 * 8]);

    for (int kt = 0; kt < nkt; ++kt) {
      const int kvb = kt * 64;
      __syncthreads();  // drains vmcnt -> buf[kt&1] ready; prev reads done

      // prefetch next K-tile into the other buffer
      if (kt + 1 < nkt) {
        const int nb = (kt + 1) & 1;
        const size_t koff = (size_t)(kvb + 64) * 3072;
        async16(kbase0 + koff, &Ks[nb][s0 * 8]);
        async16(kbase1 + koff, &Ks[nb][s1 * 8]);
      }
      const short* Kb = &Ks[kt & 1][0];

      // V frags (A-operand) straight from global, coalesced 1KB each.
      const short* vp = v2base + (size_t)kt * 4096;
      short8 vf[4][2];
#pragma unroll
      for (int dt = 0; dt < 4; ++dt) {
        vf[dt][0] = *(const short8*)(vp + (dt * 2 + 0) * 512);
        vf[dt][1] = *(const short8*)(vp + (dt * 2 + 1) * 512);
      }

      // K frags (A-operand): row t=nt*16+l15, chunk (kk*4+quad)^xk
      short8 kf[4][2];
#pragma unroll
      for (int nt = 0; nt < 4; ++nt) {
        kf[nt][0] = *(const short8*)&Kb[(nt * 16 + l15) * 64 + ((quad) ^ xk) * 8];
        kf[nt][1] = *(const short8*)&Kb[(nt * 16 + l15) * 64 + ((4 + quad) ^ xk) * 8];
      }

      // S^T = K Q^T : lane gets S^T[kv=nt*16+quad*4+reg][q=l15]
      f32x4 s[4];
#pragma unroll
      for (int nt = 0; nt < 4; ++nt) {
        s[nt] = MFMA_BF16(kf[nt][0], qf[0], ((f32x4){0.f, 0.f, 0.f, 0.f}));
        s[nt] = MFMA_BF16(kf[nt][1], qf[1], s[nt]);
      }

      // p = exp2(s); mask only on the diagonal tile (kvb+64 > qg0)
      float p[4][4];
      if (kvb + 64 <= qg0) {
#pragma unroll
        for (int nt = 0; nt < 4; ++nt)
#pragma unroll
          for (int r = 0; r < 4; ++r)
            p[nt][r] = __builtin_amdgcn_exp2f(s[nt][r]);
      } else {
        const int qrel = qg0 + l15 - kvb;
#pragma unroll
        for (int nt = 0; nt < 4; ++nt)
#pragma unroll
          for (int r = 0; r < 4; ++r) {
            const int kvl = nt * 16 + quad * 4 + r;
            p[nt][r] = (kvl <= qrel) ? __builtin_amdgcn_exp2f(s[nt][r]) : 0.f;
          }
      }

      // row sum: 15 in-lane adds + 2 cross-quad shuffles
      float rs = ((p[0][0] + p[0][1]) + (p[0][2] + p[0][3])) +
                 ((p[1][0] + p[1][1]) + (p[1][2] + p[1][3])) +
                 ((p[2][0] + p[2][1]) + (p[2][2] + p[2][3])) +
                 ((p[3][0] + p[3][1]) + (p[3][2] + p[3][3]));
      rs += __shfl_xor(rs, 16);
      rs += __shfl_xor(rs, 32);
      l_r += rs;

      // P -> LDS, layout [f][chunk][q]x16B; pair p0 = 8nt+2quad
#pragma unroll
      for (int nt = 0; nt < 4; ++nt) {
        u32 w0 = pack_bf16_trunc(p[nt][0], p[nt][1]);
        u32 w1 = pack_bf16_trunc(p[nt][2], p[nt][3]);
        const int p0 = 8 * nt + 2 * quad;
        u32* dst = (u32*)Pw + (p0 >> 4) * 256 + ((p0 >> 2) & 3) * 64 +
                   l15 * 4 + (p0 & 3);
        *(uint2*)dst = make_uint2(w0, w1);
      }
      // P frags (B-operand): contiguous b128, conflict-free
      short8 pf0 = *(const short8*)&Pw[quad * 128 + l15 * 8];
      short8 pf1 = *(const short8*)&Pw[512 + quad * 128 + l15 * 8];

      // O^T += V^T P^T : lane gets O^T[d=dt*16+quad*4+reg][q=l15]
#pragma unroll
      for (int dt = 0; dt < 4; ++dt) {
        o[dt] = MFMA_BF16(vf[dt][0], pf0, o[dt]);
        o[dt] = MFMA_BF16(vf[dt][1], pf1, o[dt]);
      }
    }

    // epilogue: normalize, transpose via per-wave LDS, coalesced bf16 store
    {
      const float inv = 1.f / l_r;
#pragma unroll
      for (int dt = 0; dt < 4; ++dt) {
        const int d = dt * 16 + quad * 4;
        u32 w0 = pack_bf16_trunc(o[dt][0] * inv, o[dt][1] * inv);
        u32 w1 = pack_bf16_trunc(o[dt][2] * inv, o[dt][3] * inv);
        *(uint2*)&Pw[(d >> 5) * 512 + l15 * 32 + (d & 31)] = make_uint2(w0, w1);
      }
      const int qq = lane >> 2, ck = lane & 3;
      const size_t yrow = (size_t)(base_row + qg0 + qq);
#pragma unroll
      for (int kkd = 0; kkd < 2; ++kkd) {
        short8 vv = *(const short8*)&Pw[kkd * 512 + qq * 32 + ck * 8];
        *(short8*)(y + yrow * 1024 + h * 64 + kkd * 32 + ck * 8) = vv;
      }
    }
    __syncthreads();  // all K/P reads of this half done before next prologue
  }
}

// ---------------------------------------------------------------------------
// launch
// ---------------------------------------------------------------------------
extern "C" void kernel_launch(void* const* d_in, const int* in_sizes, int n_in,
                              void* d_out, int out_size, void* d_ws,
                              size_t ws_size, hipStream_t stream) {
  const float* x  = (const float*)d_in[0];   // [4,2048,1024]
  const float* wa = (const float*)d_in[1];   // [3072,1024]
  const float* wp = (const float*)d_in[2];   // [1024,1024]
  float* out = (float*)d_out;                // [4,2048,1024] fp32

  char* ws = (char*)d_ws;
  short* xb  = (short*)(ws + 0);             // 16 MB (reused as vt2 later)
  short* wab = (short*)(ws + 16777216);      // 6 MB
  short* wpb = (short*)(ws + 23068672);      // 2 MB
  short* qkv = (short*)(ws + 25165824);      // 48 MB
  short* yb  = (short*)(ws + 75497472);      // 16 MB
  short* vtb = xb;  // x no longer needed after GEMM1; reuse its 16 MB

  // fused casts (x, wa with q-scale, wp): 3145728 float4 elems
  cast_all_kernel<<<12288, 256, 0, stream>>>(x, wa, wp, xb, wab, wpb);

  // qkv = x @ w_attn^T (q pre-scaled): M=8192 N=3072 K=1024 -> bf16
  // r14: 256x256 counted-vmcnt structure, 384 blocks (12 x 32), 512 thr
  gemm256_kernel<<<dim3(12, 32), 512, 0, stream>>>(xb, wab, qkv);

  // v-part of qkv -> fragment-major vt2
  vtrans_kernel<<<dim3(32, 64), 256, 0, stream>>>(qkv, vtb);

  // balanced causal flash attention -> y bf16 [8192,1024] (r10 best)
  attn_kernel<<<dim3(64, 16), 256, 0, stream>>>(qkv, vtb, yb);

  // out = y @ w_proj^T : M=8192 N=1024 K=1024 -> fp32
  gemm_bt_kernel<false><<<dim3(1024 / 128, 8192 / 128), 256, 0, stream>>>(
      yb, wpb, (void*)out, 8192, 1024, 1024);
}

// Round 8
// 226.665 us; speedup vs baseline: 1.1039x; 1.1039x over previous
//
#include <hip/hip_runtime.h>
#include <cstdint>
#include <cstddef>

typedef __attribute__((ext_vector_type(8))) short short8;
typedef __attribute__((ext_vector_type(4))) float f32x4;
typedef unsigned int u32;

#define MFMA_BF16(a, b, c) __builtin_amdgcn_mfma_f32_16x16x32_bf16((a), (b), (c), 0, 0, 0)

// ---------------------------------------------------------------------------
// helpers
// ---------------------------------------------------------------------------
__device__ __forceinline__ void async16(const void* g, void* l) {
  __builtin_amdgcn_global_load_lds(
      (const __attribute__((address_space(1))) u32*)g,
      (__attribute__((address_space(3))) u32*)l, 16, 0, 0);
}

__device__ __forceinline__ short f2bf(float f) {
  u32 u = __builtin_bit_cast(u32, f);
  u += 0x7fffu + ((u >> 16) & 1u);  // round-to-nearest-even
  return (short)(u >> 16);
}

// truncating pack: [bf16(lo) | bf16(hi)<<16] in ONE v_perm_b32
__device__ __forceinline__ u32 pack_bf16_trunc(float lo, float hi) {
  return __builtin_amdgcn_perm(__builtin_bit_cast(u32, hi),
                               __builtin_bit_cast(u32, lo), 0x07060302u);
}

// ---------------------------------------------------------------------------
// fused cast fp32 -> bf16 for x, w_attn (q-rows pre-scaled), w_proj
// region sizes (float4 units): x 2097152, wa 786432 (first 262144 scaled), wp 262144
// ---------------------------------------------------------------------------
__global__ __launch_bounds__(256) void cast_all_kernel(
    const float* __restrict__ x, const float* __restrict__ wa,
    const float* __restrict__ wp, short* __restrict__ xb,
    short* __restrict__ wab, short* __restrict__ wpb) {
  const int i = blockIdx.x * blockDim.x + threadIdx.x;
  const float4* src;
  short4* dst;
  float sc = 1.0f;
  if (i < 2097152) {
    src = (const float4*)x + i;
    dst = (short4*)xb + i;
  } else if (i < 2883584) {
    const int j = i - 2097152;
    if (j < 262144) sc = 0.18033688011112042f;  // 1/sqrt(64)*log2(e)
    src = (const float4*)wa + j;
    dst = (short4*)wab + j;
  } else {
    const int j = i - 2883584;
    src = (const float4*)wp + j;
    dst = (short4*)wpb + j;
  }
  float4 v = *src;
  short4 r;
  r.x = f2bf(v.x * sc); r.y = f2bf(v.y * sc);
  r.z = f2bf(v.z * sc); r.w = f2bf(v.w * sc);
  *dst = r;
}

// ---------------------------------------------------------------------------
// C[M][N] = A[M][K] * Bt[N][K]^T   (bf16-as-short in, fp32 accumulate)
// 128x128 tile, BK=64 — known-good m97-style structure (r14's 256² variant
// regressed: 1 block/CU + 384-on-256 grid quantization; reverted).
// XCD swizzle requires gridDim.y==64.
// r15 V_FUSE: for GEMM1's V-column tiles (bn>=2048), the epilogue writes the
// attention V-fragment layout directly into the qkv v-slots (bijective remap
//   row = b*2048 + kt*64 + h*4 + dt,  col = 2048 + kk*512,
//   within-block offset (q16*16 + l15)*8 + jb, jb=(quad&1)*4),
// reproducing exactly what vtrans_kernel used to build — so vtrans is
// DELETED (saves its 32MB round trip + launch). Per (mt,nt): acc regs 0..3
// are 4 consecutive t (t64 = kkb*32 + q16*8 + jb + reg) -> one 8B store.
// No race: qkv is write-only during GEMM1; all slots written exactly once.
// ---------------------------------------------------------------------------
template <bool OUT_BF16, bool V_FUSE>
__global__ __launch_bounds__(256) void gemm_bt_kernel(
    const short* __restrict__ A, const short* __restrict__ Bt,
    void* __restrict__ Cv, int M, int N, int K) {
  __shared__ __align__(16) short As[128 * 64];
  __shared__ __align__(16) short Bs[128 * 64];

  const int tid  = threadIdx.x;
  const int lane = tid & 63;
  const int wave = tid >> 6;
  const int quad = lane >> 4;
  const int l15  = lane & 15;

  const int id  = blockIdx.y * gridDim.x + blockIdx.x;
  const int xcd = id & 7;
  const int j   = id >> 3;
  const int by  = xcd * 8 + (j & 7);
  const int bx  = j >> 3;
  const int bm  = by * 128;
  const int bn  = bx * 128;

  const int wm = (wave >> 1) * 64;
  const int wn = (wave & 1) * 64;

  f32x4 acc[4][4];
#pragma unroll
  for (int i = 0; i < 4; ++i)
#pragma unroll
    for (int jj = 0; jj < 4; ++jj) acc[i][jj] = (f32x4){0.f, 0.f, 0.f, 0.f};

  int srow[4], scol[4];
#pragma unroll
  for (int it = 0; it < 4; ++it) {
    const int s = tid + it * 256;
    srow[it] = s >> 3;
    scol[it] = ((s & 7) ^ (srow[it] & 7)) * 8;
  }
  const int xk = l15 & 7;

  for (int k0 = 0; k0 < K; k0 += 64) {
    __syncthreads();
#pragma unroll
    for (int it = 0; it < 4; ++it) {
      const int s = tid + it * 256;
      async16(A  + (size_t)(bm + srow[it]) * K + k0 + scol[it], &As[s * 8]);
      async16(Bt + (size_t)(bn + srow[it]) * K + k0 + scol[it], &Bs[s * 8]);
    }
    __syncthreads();

    short8 af[4][2], bf[4][2];
#pragma unroll
    for (int mt = 0; mt < 4; ++mt) {
      const int ra = (wm + mt * 16 + l15) * 64;
      af[mt][0] = *(const short8*)&As[ra + ((quad) ^ xk) * 8];
      af[mt][1] = *(const short8*)&As[ra + ((4 + quad) ^ xk) * 8];
    }
#pragma unroll
    for (int nt = 0; nt < 4; ++nt) {
      const int rb = (wn + nt * 16 + l15) * 64;
      bf[nt][0] = *(const short8*)&Bs[rb + ((quad) ^ xk) * 8];
      bf[nt][1] = *(const short8*)&Bs[rb + ((4 + quad) ^ xk) * 8];
    }
#pragma unroll
    for (int kk = 0; kk < 2; ++kk)
#pragma unroll
      for (int mt = 0; mt < 4; ++mt)
#pragma unroll
        for (int nt = 0; nt < 4; ++nt)
          acc[mt][nt] = MFMA_BF16(af[mt][kk], bf[nt][kk], acc[mt][nt]);
  }

  if (V_FUSE && bn >= 2048) {
    // V-fragment epilogue (see header comment). One 8B store per (mt,nt).
    const int b   = bm >> 11;
    const int btt = bm & 2047;
#pragma unroll
    for (int mt = 0; mt < 4; ++mt) {
      const int tt   = btt + wm + mt * 16;       // t of rows, + quad*4
      const int kt   = tt >> 6;
      const int t64b = (tt & 63) + quad * 4;
      const int kkb  = t64b >> 5;
      const int q16  = (t64b >> 3) & 3;
      const int jb   = t64b & 7;                 // 0 or 4
#pragma unroll
      for (int nt = 0; nt < 4; ++nt) {
        const int dcol = bn - 2048 + wn + nt * 16;  // + l15
        const int h  = dcol >> 6;
        const int dt = (dcol >> 4) & 3;
        short* dst = (short*)Cv +
            (size_t)(b * 2048 + kt * 64 + h * 4 + dt) * 3072 + 2048 +
            kkb * 512 + (q16 * 16 + l15) * 8 + jb;
        u32 w0 = (u32)(unsigned short)f2bf(acc[mt][nt][0]) |
                 ((u32)(unsigned short)f2bf(acc[mt][nt][1]) << 16);
        u32 w1 = (u32)(unsigned short)f2bf(acc[mt][nt][2]) |
                 ((u32)(unsigned short)f2bf(acc[mt][nt][3]) << 16);
        *(uint2*)dst = make_uint2(w0, w1);
      }
    }
  } else {
#pragma unroll
    for (int mt = 0; mt < 4; ++mt) {
      const int r0e = bm + wm + mt * 16 + quad * 4;
#pragma unroll
      for (int nt = 0; nt < 4; ++nt) {
        const int c = bn + wn + nt * 16 + l15;
#pragma unroll
        for (int reg = 0; reg < 4; ++reg) {
          float v = acc[mt][nt][reg];
          if (OUT_BF16)
            ((short*)Cv)[(size_t)(r0e + reg) * N + c] = f2bf(v);
          else
            ((float*)Cv)[(size_t)(r0e + reg) * N + c] = v;
        }
      }
    }
  }
}

// ---------------------------------------------------------------------------
// Causal flash attention — r10 structure (best measured: 67.1 us), with V
// fragments read from the fused qkv v-slot layout (see gemm_bt V_FUSE):
//   vf[dt][kk] <- qkv[(b*2048 + kt*64 + h*4 + dt)*3072 + 2048 + kk*512
//                     + lane*8]   (1KB coalesced per fragment, as before)
// ---------------------------------------------------------------------------
__global__ __launch_bounds__(256, 4) void attn_kernel(
    const short* __restrict__ qkv, short* __restrict__ y) {
  __shared__ __align__(16) short Ks[2][4096];  // [buf][row t][64 d]
  __shared__ __align__(16) short Ps[4][1024];  // per-wave P / epilogue

  const int bh    = blockIdx.x;     // 0..63  (XCD = bh % 8 for all pairi)
  const int pairi = blockIdx.y;     // 0..15
  const int b = bh >> 4, h = bh & 15;
  const int tid  = threadIdx.x;
  const int lane = tid & 63;
  const int wave = tid >> 6;
  const int quad = lane >> 4, l15 = lane & 15;
  const int base_row = b * 2048;
  short* Pw = &Ps[wave][0];

  // K staging: slot s -> row=s>>3, chunk=(s&7)^(row&7); dst shorts s*8
  const int s0 = tid, s1 = tid + 256;
  const int r0s = s0 >> 3, c0s = (s0 & 7) ^ (r0s & 7);
  const int r1s = s1 >> 3, c1s = (s1 & 7) ^ (r1s & 7);
  const short* kbase0 = qkv + (size_t)(base_row + r0s) * 3072 + 1024 + h * 64 + c0s * 8;
  const short* kbase1 = qkv + (size_t)(base_row + r1s) * 3072 + 1024 + h * 64 + c1s * 8;

  // V fragment base (fused layout in qkv v-slots)
  const short* vbaseA = qkv + ((size_t)base_row + h * 4) * 3072 + 2048 +
                        (size_t)lane * 8;

  const int xk = l15 & 7;  // frag-read chunk XOR

  for (int half = 0; half < 2; ++half) {
    const int qi  = half ? (31 - pairi) : pairi;  // 64-row q-tile index
    const int nkt = qi + 1;                       // kv tiles 0..qi
    const int qg0 = qi * 64 + wave * 16;          // this wave's q-group base

    // Q fragments (B-operand): lane holds Q[q=l15][d=quad*8..+7] per half
    short8 qf[2];
    {
      const short* qp = qkv +
          (size_t)(base_row + qg0 + l15) * 3072 + h * 64 + quad * 8;
      qf[0] = *(const short8*)qp;
      qf[1] = *(const short8*)(qp + 32);
    }
    float l_r = 0.f;
    f32x4 o[4];
#pragma unroll
    for (int dt = 0; dt < 4; ++dt) o[dt] = (f32x4){0.f, 0.f, 0.f, 0.f};

    // prologue: stage K-tile 0 into buffer 0
    async16(kbase0, &Ks[0][s0 * 8]);
    async16(kbase1, &Ks[0][s1 * 8]);

    for (int kt = 0; kt < nkt; ++kt) {
      const int kvb = kt * 64;
      __syncthreads();  // drains vmcnt -> buf[kt&1] ready; prev reads done

      // prefetch next K-tile into the other buffer
      if (kt + 1 < nkt) {
        const int nb = (kt + 1) & 1;
        const size_t koff = (size_t)(kvb + 64) * 3072;
        async16(kbase0 + koff, &Ks[nb][s0 * 8]);
        async16(kbase1 + koff, &Ks[nb][s1 * 8]);
      }
      const short* Kb = &Ks[kt & 1][0];

      // V frags (A-operand) straight from global, coalesced 1KB each.
      const short* vp = vbaseA + (size_t)kt * 64 * 3072;
      short8 vf[4][2];
#pragma unroll
      for (int dt = 0; dt < 4; ++dt) {
        vf[dt][0] = *(const short8*)(vp + (size_t)dt * 3072);
        vf[dt][1] = *(const short8*)(vp + (size_t)dt * 3072 + 512);
      }

      // K frags (A-operand): row t=nt*16+l15, chunk (kk*4+quad)^xk
      short8 kf[4][2];
#pragma unroll
      for (int nt = 0; nt < 4; ++nt) {
        kf[nt][0] = *(const short8*)&Kb[(nt * 16 + l15) * 64 + ((quad) ^ xk) * 8];
        kf[nt][1] = *(const short8*)&Kb[(nt * 16 + l15) * 64 + ((4 + quad) ^ xk) * 8];
      }

      // S^T = K Q^T : lane gets S^T[kv=nt*16+quad*4+reg][q=l15]
      f32x4 s[4];
#pragma unroll
      for (int nt = 0; nt < 4; ++nt) {
        s[nt] = MFMA_BF16(kf[nt][0], qf[0], ((f32x4){0.f, 0.f, 0.f, 0.f}));
        s[nt] = MFMA_BF16(kf[nt][1], qf[1], s[nt]);
      }

      // p = exp2(s); mask only on the diagonal tile (kvb+64 > qg0)
      float p[4][4];
      if (kvb + 64 <= qg0) {
#pragma unroll
        for (int nt = 0; nt < 4; ++nt)
#pragma unroll
          for (int r = 0; r < 4; ++r)
            p[nt][r] = __builtin_amdgcn_exp2f(s[nt][r]);
      } else {
        const int qrel = qg0 + l15 - kvb;
#pragma unroll
        for (int nt = 0; nt < 4; ++nt)
#pragma unroll
          for (int r = 0; r < 4; ++r) {
            const int kvl = nt * 16 + quad * 4 + r;
            p[nt][r] = (kvl <= qrel) ? __builtin_amdgcn_exp2f(s[nt][r]) : 0.f;
          }
      }

      // row sum: 15 in-lane adds + 2 cross-quad shuffles
      float rs = ((p[0][0] + p[0][1]) + (p[0][2] + p[0][3])) +
                 ((p[1][0] + p[1][1]) + (p[1][2] + p[1][3])) +
                 ((p[2][0] + p[2][1]) + (p[2][2] + p[2][3])) +
                 ((p[3][0] + p[3][1]) + (p[3][2] + p[3][3]));
      rs += __shfl_xor(rs, 16);
      rs += __shfl_xor(rs, 32);
      l_r += rs;

      // P -> LDS, layout [f][chunk][q]x16B; pair p0 = 8nt+2quad
#pragma unroll
      for (int nt = 0; nt < 4; ++nt) {
        u32 w0 = pack_bf16_trunc(p[nt][0], p[nt][1]);
        u32 w1 = pack_bf16_trunc(p[nt][2], p[nt][3]);
        const int p0 = 8 * nt + 2 * quad;
        u32* dst = (u32*)Pw + (p0 >> 4) * 256 + ((p0 >> 2) & 3) * 64 +
                   l15 * 4 + (p0 & 3);
        *(uint2*)dst = make_uint2(w0, w1);
      }
      // P frags (B-operand): contiguous b128, conflict-free
      short8 pf0 = *(const short8*)&Pw[quad * 128 + l15 * 8];
      short8 pf1 = *(const short8*)&Pw[512 + quad * 128 + l15 * 8];

      // O^T += V^T P^T : lane gets O^T[d=dt*16+quad*4+reg][q=l15]
#pragma unroll
      for (int dt = 0; dt < 4; ++dt) {
        o[dt] = MFMA_BF16(vf[dt][0], pf0, o[dt]);
        o[dt] = MFMA_BF16(vf[dt][1], pf1, o[dt]);
      }
    }

    // epilogue: normalize, transpose via per-wave LDS, coalesced bf16 store
    {
      const float inv = 1.f / l_r;
#pragma unroll
      for (int dt = 0; dt < 4; ++dt) {
        const int d = dt * 16 + quad * 4;
        u32 w0 = pack_bf16_trunc(o[dt][0] * inv, o[dt][1] * inv);
        u32 w1 = pack_bf16_trunc(o[dt][2] * inv, o[dt][3] * inv);
        *(uint2*)&Pw[(d >> 5) * 512 + l15 * 32 + (d & 31)] = make_uint2(w0, w1);
      }
      const int qq = lane >> 2, ck = lane & 3;
      const size_t yrow = (size_t)(base_row + qg0 + qq);
#pragma unroll
      for (int kkd = 0; kkd < 2; ++kkd) {
        short8 vv = *(const short8*)&Pw[kkd * 512 + qq * 32 + ck * 8];
        *(short8*)(y + yrow * 1024 + h * 64 + kkd * 32 + ck * 8) = vv;
      }
    }
    __syncthreads();  // all K/P reads of this half done before next prologue
  }
}

// ---------------------------------------------------------------------------
// launch
// ---------------------------------------------------------------------------
extern "C" void kernel_launch(void* const* d_in, const int* in_sizes, int n_in,
                              void* d_out, int out_size, void* d_ws,
                              size_t ws_size, hipStream_t stream) {
  const float* x  = (const float*)d_in[0];   // [4,2048,1024]
  const float* wa = (const float*)d_in[1];   // [3072,1024]
  const float* wp = (const float*)d_in[2];   // [1024,1024]
  float* out = (float*)d_out;                // [4,2048,1024] fp32

  char* ws = (char*)d_ws;
  short* xb  = (short*)(ws + 0);             // 16 MB
  short* wab = (short*)(ws + 16777216);      // 6 MB
  short* wpb = (short*)(ws + 23068672);      // 2 MB
  short* qkv = (short*)(ws + 25165824);      // 48 MB (v-slots hold fragments)
  short* yb  = (short*)(ws + 75497472);      // 16 MB

  // fused casts (x, wa with q-scale, wp): 3145728 float4 elems
  cast_all_kernel<<<12288, 256, 0, stream>>>(x, wa, wp, xb, wab, wpb);

  // qkv = x @ w_attn^T (q pre-scaled): M=8192 N=3072 K=1024 -> bf16,
  // V-columns written directly in attn fragment layout (vtrans fused away)
  gemm_bt_kernel<true, true><<<dim3(3072 / 128, 8192 / 128), 256, 0, stream>>>(
      xb, wab, (void*)qkv, 8192, 3072, 1024);

  // balanced causal flash attention -> y bf16 [8192,1024]
  attn_kernel<<<dim3(64, 16), 256, 0, stream>>>(qkv, yb);

  // out = y @ w_proj^T : M=8192 N=1024 K=1024 -> fp32
  gemm_bt_kernel<false, false><<<dim3(1024 / 128, 8192 / 128), 256, 0, stream>>>(
      yb, wpb, (void*)out, 8192, 1024, 1024);
}